// Round 2
// baseline (294.440 us; speedup 1.0000x reference)
//
#include <hip/hip_runtime.h>

// out[b,n,s] = softmax_s( sum_k tanh(enc[s,b,n,:]·W[k,:] + b[k]) * dec[b,n,k] )
// S=64, B=32, N=325, H=64, fp32. Split-bf16 MFMA (3-term ah·bh+al·bh+ah·bl).
//
// R6 (254.0us total): flattened energy kernel, one 32-row tile per wave,
// one-shot load->wait->compute->exit. rocprof top-5 = harness 650MiB poison
// fills (~100us each @85% HBM) => kernels are <99us each; energy_k's only
// structural flaw is the full vmcnt drain between load and compute per wave.
// R7: software-pipelined energy_k. Each wave owns 4 consecutive 32-row tiles;
// per tile: pack(raw_t) -> issue loads(raw_{t+1}) -> MFMA/tanh/reduce/store.
// Compute (~1500-2500cyc) hides HBM latency (~900cyc); VMEM queue stays fed.
// Also: fused 2*log2e into one exp2 constant; incremental bn wrap instead of
// per-tile magic-mod. pack_w / softmax_k unchanged (verified).
// R8: identical resubmit of R7 (bench infra failed; kernel never ran).

constexpr int S = 64, B = 32, N = 325, H = 64;
constexpr int BN = B * N;        // 10400
constexpr int SBN = S * BN;      // 665600
constexpr int NWAVE = SBN / 128; // 5200 waves, 128 rows (4 tiles) each
constexpr int NBLK = NWAVE / 4;  // 1300 blocks

typedef __attribute__((ext_vector_type(8))) short short8;  // 8 bf16
typedef __attribute__((ext_vector_type(4))) float f32x4;

union FragU { unsigned u[4]; short8 s8; uint4 v4; };

__device__ inline unsigned pack_hi(float x0, float x1, float& r0, float& r1) {
    unsigned u0 = __builtin_bit_cast(unsigned, x0);
    unsigned u1 = __builtin_bit_cast(unsigned, x1);
    r0 = x0 - __builtin_bit_cast(float, u0 & 0xffff0000u);  // exact residual
    r1 = x1 - __builtin_bit_cast(float, u1 & 0xffff0000u);
    return (u0 >> 16) | (u1 & 0xffff0000u);
}
__device__ inline unsigned pack_bf(float x0, float x1) {
    return (__builtin_bit_cast(unsigned, x0) >> 16) |
           (__builtin_bit_cast(unsigned, x1) & 0xffff0000u);
}

// ---- prep: W -> per-lane MFMA B-fragments (hi/lo), 16 KB at ws+0 ----
__global__ void pack_w(const float* __restrict__ W, uint4* __restrict__ wp) {
    int idx = blockIdx.x * blockDim.x + threadIdx.x;
    if (idx >= 512) return;
    int q = idx >> 7, kc = (idx >> 6) & 1, lane = idx & 63;
    int col = lane & 15, grp = lane >> 4;
    const float4* wpt = (const float4*)(W + (q * 16 + col) * H + kc * 32 + grp * 8);
    float4 w0 = wpt[0], w1 = wpt[1];
    float r0, r1, r2, r3, r4, r5, r6, r7;
    FragU hi, lo;
    hi.u[0] = pack_hi(w0.x, w0.y, r0, r1);
    hi.u[1] = pack_hi(w0.z, w0.w, r2, r3);
    hi.u[2] = pack_hi(w1.x, w1.y, r4, r5);
    hi.u[3] = pack_hi(w1.z, w1.w, r6, r7);
    lo.u[0] = pack_bf(r0, r1); lo.u[1] = pack_bf(r2, r3);
    lo.u[2] = pack_bf(r4, r5); lo.u[3] = pack_bf(r6, r7);
    wp[((q * 2 + kc) * 2 + 0) * 64 + lane] = hi.v4;
    wp[((q * 2 + kc) * 2 + 1) * 64 + lane] = lo.v4;
}

// ---- kernel A: e[sbn] = sum_k tanh(enc[sbn,:]·W[k,:]+b[k]) * dec[sbn%BN, k] ----
// wave handles 128 consecutive rows = 4 tiles of 32; software-pipelined loads.
__global__ __launch_bounds__(256) void energy_k(
    const float* __restrict__ enc, const float* __restrict__ dec,
    const float* __restrict__ bias, const uint4* __restrict__ wp,
    float* __restrict__ e)
{
    const int lane = threadIdx.x & 63;
    const int wv   = threadIdx.x >> 6;
    const int col  = lane & 15, grp = lane >> 4;
    const int wave_id = blockIdx.x * 4 + wv;
    const int row_base = wave_id * 128;

    float bias_v[4];
#pragma unroll
    for (int q = 0; q < 4; ++q) bias_v[q] = bias[q * 16 + col];

    // raw staging registers for the in-flight tile (single bank; WAR on regs
    // orders load-issue after pack's reads, compiler may rename = free dbuf)
    float4 raw[8];

    // issue tile 0 loads
    {
#pragma unroll
        for (int mt = 0; mt < 2; ++mt) {
            const float4* er = (const float4*)(enc + (size_t)(row_base + mt * 16 + col) * H) + grp * 2;
#pragma unroll
            for (int kc = 0; kc < 2; ++kc) {
                raw[mt * 4 + kc * 2 + 0] = er[kc * 8 + 0];
                raw[mt * 4 + kc * 2 + 1] = er[kc * 8 + 1];
            }
        }
    }

    // per-(mt,r) bn index, updated incrementally (+32 mod BN) per tile
    unsigned bnv[2][4];

#pragma unroll
    for (int t = 0; t < 4; ++t) {
        const int row0 = row_base + t * 32;

        // ---- pack current raw -> A fragments (waits vmcnt for raw) ----
        FragU a_hi[2][2], a_lo[2][2];
#pragma unroll
        for (int mt = 0; mt < 2; ++mt)
#pragma unroll
            for (int kc = 0; kc < 2; ++kc) {
                float4 x0 = raw[mt * 4 + kc * 2 + 0];
                float4 x1 = raw[mt * 4 + kc * 2 + 1];
                float r0, r1, r2, r3, r4, r5, r6, r7;
                a_hi[mt][kc].u[0] = pack_hi(x0.x, x0.y, r0, r1);
                a_hi[mt][kc].u[1] = pack_hi(x0.z, x0.w, r2, r3);
                a_hi[mt][kc].u[2] = pack_hi(x1.x, x1.y, r4, r5);
                a_hi[mt][kc].u[3] = pack_hi(x1.z, x1.w, r6, r7);
                a_lo[mt][kc].u[0] = pack_bf(r0, r1);
                a_lo[mt][kc].u[1] = pack_bf(r2, r3);
                a_lo[mt][kc].u[2] = pack_bf(r4, r5);
                a_lo[mt][kc].u[3] = pack_bf(r6, r7);
            }

        // ---- issue next tile's loads (overlap with compute below) ----
        if (t < 3) {
            const int rown = row_base + (t + 1) * 32;
#pragma unroll
            for (int mt = 0; mt < 2; ++mt) {
                const float4* er = (const float4*)(enc + (size_t)(rown + mt * 16 + col) * H) + grp * 2;
#pragma unroll
                for (int kc = 0; kc < 2; ++kc) {
                    raw[mt * 4 + kc * 2 + 0] = er[kc * 8 + 0];
                    raw[mt * 4 + kc * 2 + 1] = er[kc * 8 + 1];
                }
            }
        }

        // ---- bn / dec offsets for this tile ----
        int doff[2][4];
#pragma unroll
        for (int mt = 0; mt < 2; ++mt)
#pragma unroll
            for (int r = 0; r < 4; ++r) {
                if (t == 0) {
                    unsigned sbn = (unsigned)(row0 + mt * 16 + grp * 4 + r);
                    bnv[mt][r] = sbn % (unsigned)BN;   // magic-mul once
                } else {
                    unsigned b2 = bnv[mt][r] + 32u;
                    bnv[mt][r] = (b2 >= (unsigned)BN) ? b2 - (unsigned)BN : b2;
                }
                doff[mt][r] = (int)(bnv[mt][r] * (unsigned)H) + col;
            }

        float part[2][4];
#pragma unroll
        for (int mt = 0; mt < 2; ++mt)
#pragma unroll
            for (int r = 0; r < 4; ++r) part[mt][r] = 0.0f;

#pragma unroll
        for (int q = 0; q < 4; ++q) {
            f32x4 acc[2];
            acc[0] = (f32x4){0.f, 0.f, 0.f, 0.f};
            acc[1] = (f32x4){0.f, 0.f, 0.f, 0.f};
#pragma unroll
            for (int kc = 0; kc < 2; ++kc) {
                FragU bh, bl;
                bh.v4 = wp[((q * 2 + kc) * 2 + 0) * 64 + lane];
                bl.v4 = wp[((q * 2 + kc) * 2 + 1) * 64 + lane];
#pragma unroll
                for (int mt = 0; mt < 2; ++mt) {
                    acc[mt] = __builtin_amdgcn_mfma_f32_16x16x32_bf16(a_hi[mt][kc].s8, bh.s8, acc[mt], 0, 0, 0);
                    acc[mt] = __builtin_amdgcn_mfma_f32_16x16x32_bf16(a_lo[mt][kc].s8, bh.s8, acc[mt], 0, 0, 0);
                    acc[mt] = __builtin_amdgcn_mfma_f32_16x16x32_bf16(a_hi[mt][kc].s8, bl.s8, acc[mt], 0, 0, 0);
                }
            }
            // C/D layout: lane holds energy[m = grp*4+r (+16mt)][kout = q*16+col]
#pragma unroll
            for (int mt = 0; mt < 2; ++mt)
#pragma unroll
                for (int r = 0; r < 4; ++r) {
                    float a = acc[mt][r] + bias_v[q];
                    // tanh(a) = 1 - 2/(exp2(a*2*log2e)+1); fused constant
                    float z = __builtin_amdgcn_exp2f(a * 2.8853900817779268f);
                    float rr = __builtin_amdgcn_rcpf(z + 1.0f);
                    float tt = fmaf(-2.0f, rr, 1.0f);
                    part[mt][r] = fmaf(tt, dec[doff[mt][r] + q * 16], part[mt][r]);
                }
        }

        // reduce over the 16 kout-lanes (xor bits 0-3 stay within the 16-group)
#pragma unroll
        for (int mt = 0; mt < 2; ++mt)
#pragma unroll
            for (int r = 0; r < 4; ++r) {
                float v = part[mt][r];
                v += __shfl_xor(v, 1, 64);
                v += __shfl_xor(v, 2, 64);
                v += __shfl_xor(v, 4, 64);
                v += __shfl_xor(v, 8, 64);
                part[mt][r] = v;
            }

        // lanes col<8 store: value index sel = col&7 -> (mt = col>>2, r = col&3)
        float va = (col & 1) ? part[0][1] : part[0][0];
        float vb = (col & 1) ? part[0][3] : part[0][2];
        float vc = (col & 1) ? part[1][1] : part[1][0];
        float vd = (col & 1) ? part[1][3] : part[1][2];
        float ve = (col & 2) ? vb : va;
        float vf = (col & 2) ? vd : vc;
        float vo = (col & 4) ? vf : ve;
        if (col < 8)
            e[row0 + ((col >> 2) & 1) * 16 + grp * 4 + (col & 3)] = vo;
    }
}

// ---- kernel B: softmax over s per bn; 64bn x 64s LDS tile, coalesced both ways
__global__ __launch_bounds__(256) void softmax_k(
    const float* __restrict__ e,    // (S, BN)
    float* __restrict__ out)        // (BN, S)
{
    __shared__ float Et[64 * 65];
    __shared__ float Mred[4][64], Sred[4][64], Mfin[64], Rfin[64];

    const int t = threadIdx.x;
    const int bn0 = blockIdx.x * 64;
    const int lane = t & 63, w = t >> 6;

    // stage: Et[s][bn_loc], reads of e coalesced along bn
#pragma unroll
    for (int i = 0; i < 16; ++i) {
        int s = w * 16 + i;
        float v = (bn0 + lane < BN) ? e[s * BN + bn0 + lane] : 0.0f;
        Et[s * 65 + lane] = v;
    }
    __syncthreads();

    // per-bn max then sum(exp), 4 threads per bn
    {
        const int bn_loc = t & 63, sq = t >> 6;
        float m = -1e30f;
#pragma unroll
        for (int i = 0; i < 16; ++i)
            m = fmaxf(m, Et[(sq * 16 + i) * 65 + bn_loc]);
        Mred[sq][bn_loc] = m;
    }
    __syncthreads();
    {
        const int bn_loc = t & 63, sq = t >> 6;
        float m = fmaxf(fmaxf(Mred[0][bn_loc], Mred[1][bn_loc]),
                        fmaxf(Mred[2][bn_loc], Mred[3][bn_loc]));
        float sum = 0.0f;
#pragma unroll
        for (int i = 0; i < 16; ++i)
            sum += __expf(Et[(sq * 16 + i) * 65 + bn_loc] - m);
        Sred[sq][bn_loc] = sum;
        if (sq == 0) Mfin[bn_loc] = m;
    }
    __syncthreads();
    if ((t >> 6) == 0) {
        const int bn_loc = t & 63;
        float sum = Sred[0][bn_loc] + Sred[1][bn_loc] + Sred[2][bn_loc] + Sred[3][bn_loc];
        Rfin[bn_loc] = __builtin_amdgcn_rcpf(sum);
    }
    __syncthreads();

    // write out[bn][s], lanes -> s (coalesced)
    const int s_out = t & 63, bq = t >> 6;
#pragma unroll
    for (int j = 0; j < 16; ++j) {
        int bn_loc = bq * 16 + j;
        if (bn0 + bn_loc < BN) {
            float p = __expf(Et[s_out * 65 + bn_loc] - Mfin[bn_loc]) * Rfin[bn_loc];
            out[(bn0 + bn_loc) * S + s_out] = p;
        }
    }
}

extern "C" void kernel_launch(void* const* d_in, const int* in_sizes, int n_in,
                              void* d_out, int out_size, void* d_ws, size_t ws_size,
                              hipStream_t stream) {
    const float* enc  = (const float*)d_in[0];
    const float* dec  = (const float*)d_in[1];
    const float* W    = (const float*)d_in[2];
    const float* bias = (const float*)d_in[3];
    float* out        = (float*)d_out;

    uint4* wp = (uint4*)d_ws;                          // 16 KB
    float* e  = (float*)((char*)d_ws + 65536);         // 2.66 MB

    pack_w<<<2, 256, 0, stream>>>(W, wp);
    energy_k<<<NBLK, 256, 0, stream>>>(enc, dec, bias, wp, e);   // 1300 blocks
    softmax_k<<<(BN + 63) / 64, 256, 0, stream>>>(e, out);       // 163 blocks
}

// Round 3
// 258.306 us; speedup vs baseline: 1.1399x; 1.1399x over previous
//
#include <hip/hip_runtime.h>

// out[b,n,s] = softmax_s( sum_k tanh(enc[s,b,n,:]·W[k,:] + b[k]) * dec[b,n,k] )
// S=64, B=32, N=325, H=64, fp32. Split-bf16 MFMA (3-term ah·bh+al·bh+ah·bl).
//
// R6 (254us total): flattened, one 32-row tile/wave, one-shot. energy ~45us.
// R7/R8 (294us): 4-tile software pipeline REGRESSED energy_k to 113us —
//   rocprof: Occupancy 18% (1.4 waves/SIMD), VALUBusy 17.6%, MfmaUtil 5.5%,
//   HBM 15%. Pipeline state (raw[8]+bnv) ballooned regs; occupancy collapsed;
//   latency-bound. Lesson: with one-shot waves, OCCUPANCY is the pipeline —
//   every resident wave has its loads in flight from birth.
// R9: one-shot again, 16-row tile/wave (half of R6) to minimize live state:
//   frags 16 regs, ~70 VGPR est, __launch_bounds__(256,6) caps at ~85
//   (>=24 waves/CU). dec values prefetched right after enc load issue so
//   their latency hides under the enc vmcnt wait. Fused-exp2 tanh kept.
//   41600 waves / 10400 blocks. pack_w / softmax_k unchanged (verified).

constexpr int S = 64, B = 32, N = 325, H = 64;
constexpr int BN = B * N;        // 10400
constexpr int SBN = S * BN;      // 665600
constexpr int NBLK = SBN / 64;   // 10400 blocks (4 waves x 16 rows each)

typedef __attribute__((ext_vector_type(8))) short short8;  // 8 bf16
typedef __attribute__((ext_vector_type(4))) float f32x4;

union FragU { unsigned u[4]; short8 s8; uint4 v4; };

__device__ inline unsigned pack_hi(float x0, float x1, float& r0, float& r1) {
    unsigned u0 = __builtin_bit_cast(unsigned, x0);
    unsigned u1 = __builtin_bit_cast(unsigned, x1);
    r0 = x0 - __builtin_bit_cast(float, u0 & 0xffff0000u);  // exact residual
    r1 = x1 - __builtin_bit_cast(float, u1 & 0xffff0000u);
    return (u0 >> 16) | (u1 & 0xffff0000u);
}
__device__ inline unsigned pack_bf(float x0, float x1) {
    return (__builtin_bit_cast(unsigned, x0) >> 16) |
           (__builtin_bit_cast(unsigned, x1) & 0xffff0000u);
}

// ---- prep: W -> per-lane MFMA B-fragments (hi/lo), 16 KB at ws+0 ----
__global__ void pack_w(const float* __restrict__ W, uint4* __restrict__ wp) {
    int idx = blockIdx.x * blockDim.x + threadIdx.x;
    if (idx >= 512) return;
    int q = idx >> 7, kc = (idx >> 6) & 1, lane = idx & 63;
    int col = lane & 15, grp = lane >> 4;
    const float4* wpt = (const float4*)(W + (q * 16 + col) * H + kc * 32 + grp * 8);
    float4 w0 = wpt[0], w1 = wpt[1];
    float r0, r1, r2, r3, r4, r5, r6, r7;
    FragU hi, lo;
    hi.u[0] = pack_hi(w0.x, w0.y, r0, r1);
    hi.u[1] = pack_hi(w0.z, w0.w, r2, r3);
    hi.u[2] = pack_hi(w1.x, w1.y, r4, r5);
    hi.u[3] = pack_hi(w1.z, w1.w, r6, r7);
    lo.u[0] = pack_bf(r0, r1); lo.u[1] = pack_bf(r2, r3);
    lo.u[2] = pack_bf(r4, r5); lo.u[3] = pack_bf(r6, r7);
    wp[((q * 2 + kc) * 2 + 0) * 64 + lane] = hi.v4;
    wp[((q * 2 + kc) * 2 + 1) * 64 + lane] = lo.v4;
}

// ---- kernel A: e[sbn] = sum_k tanh(enc[sbn,:]·W[k,:]+b[k]) * dec[sbn%BN, k] ----
// one 16-row tile per wave, one-shot: issue enc loads, issue dec loads,
// pack, MFMA, tanh-dot, shuffle-reduce, store, exit. Minimal live state.
__global__ __launch_bounds__(256, 6) void energy_k(
    const float* __restrict__ enc, const float* __restrict__ dec,
    const float* __restrict__ bias, const uint4* __restrict__ wp,
    float* __restrict__ e)
{
    const int lane = threadIdx.x & 63;
    const int wv   = threadIdx.x >> 6;
    const int col  = lane & 15, grp = lane >> 4;
    const int row0 = (blockIdx.x * 4 + wv) * 16;   // 41600 waves * 16 rows

    // ---- issue enc loads: 16 consecutive rows, lane (col,grp) reads
    //      row row0+col, floats [kc*32 + grp*8 .. +8) ----
    const float4* er = (const float4*)(enc + (size_t)(row0 + col) * H) + grp * 2;
    float4 x00 = er[0];          // kc=0
    float4 x01 = er[1];
    float4 x10 = er[8];          // kc=1 (+128B)
    float4 x11 = er[9];

    // ---- dec prefetch (addresses data-independent; latency hides under
    //      the enc wait). lane needs dec[bn(row0+grp*4+r)][col + q*16] ----
    int doff[4];
#pragma unroll
    for (int r = 0; r < 4; ++r) {
        unsigned sbn = (unsigned)(row0 + grp * 4 + r);
        unsigned bn  = sbn % (unsigned)BN;           // magic-mul
        doff[r] = (int)(bn * (unsigned)H) + col;
    }
    float dv[16];
#pragma unroll
    for (int q = 0; q < 4; ++q)
#pragma unroll
        for (int r = 0; r < 4; ++r)
            dv[q * 4 + r] = dec[doff[r] + q * 16];

    float bias_v[4];
#pragma unroll
    for (int q = 0; q < 4; ++q) bias_v[q] = bias[q * 16 + col];

    // ---- pack enc -> A fragments (waits on enc vmcnt here) ----
    FragU a_hi[2], a_lo[2];
#pragma unroll
    for (int kc = 0; kc < 2; ++kc) {
        float4 x0 = kc ? x10 : x00;
        float4 x1 = kc ? x11 : x01;
        float r0, r1, r2, r3, r4, r5, r6, r7;
        a_hi[kc].u[0] = pack_hi(x0.x, x0.y, r0, r1);
        a_hi[kc].u[1] = pack_hi(x0.z, x0.w, r2, r3);
        a_hi[kc].u[2] = pack_hi(x1.x, x1.y, r4, r5);
        a_hi[kc].u[3] = pack_hi(x1.z, x1.w, r6, r7);
        a_lo[kc].u[0] = pack_bf(r0, r1);
        a_lo[kc].u[1] = pack_bf(r2, r3);
        a_lo[kc].u[2] = pack_bf(r4, r5);
        a_lo[kc].u[3] = pack_bf(r6, r7);
    }

    float part[4];
#pragma unroll
    for (int r = 0; r < 4; ++r) part[r] = 0.0f;

#pragma unroll
    for (int q = 0; q < 4; ++q) {
        f32x4 acc = (f32x4){0.f, 0.f, 0.f, 0.f};
#pragma unroll
        for (int kc = 0; kc < 2; ++kc) {
            FragU bh, bl;
            bh.v4 = wp[((q * 2 + kc) * 2 + 0) * 64 + lane];
            bl.v4 = wp[((q * 2 + kc) * 2 + 1) * 64 + lane];
            acc = __builtin_amdgcn_mfma_f32_16x16x32_bf16(a_hi[kc].s8, bh.s8, acc, 0, 0, 0);
            acc = __builtin_amdgcn_mfma_f32_16x16x32_bf16(a_lo[kc].s8, bh.s8, acc, 0, 0, 0);
            acc = __builtin_amdgcn_mfma_f32_16x16x32_bf16(a_hi[kc].s8, bl.s8, acc, 0, 0, 0);
        }
        // C/D layout: lane holds energy[m = grp*4+r][kout = q*16+col]
#pragma unroll
        for (int r = 0; r < 4; ++r) {
            float a = acc[r] + bias_v[q];
            // tanh(a) = 1 - 2/(exp2(a*2*log2e)+1)
            float z  = __builtin_amdgcn_exp2f(a * 2.8853900817779268f);
            float rr = __builtin_amdgcn_rcpf(z + 1.0f);
            float tt = fmaf(-2.0f, rr, 1.0f);
            part[r]  = fmaf(tt, dv[q * 4 + r], part[r]);
        }
    }

    // reduce over the 16 kout-lanes (xor bits 0-3 stay within the 16-group)
#pragma unroll
    for (int r = 0; r < 4; ++r) {
        float v = part[r];
        v += __shfl_xor(v, 1, 64);
        v += __shfl_xor(v, 2, 64);
        v += __shfl_xor(v, 4, 64);
        v += __shfl_xor(v, 8, 64);
        part[r] = v;
    }

    // lanes col<4 store: e[row0 + grp*4 + col] = part[col]
    float va = (col & 1) ? part[1] : part[0];
    float vb = (col & 1) ? part[3] : part[2];
    float vo = (col & 2) ? vb : va;
    if (col < 4)
        e[row0 + grp * 4 + col] = vo;
}

// ---- kernel B: softmax over s per bn; 64bn x 64s LDS tile, coalesced both ways
__global__ __launch_bounds__(256) void softmax_k(
    const float* __restrict__ e,    // (S, BN)
    float* __restrict__ out)        // (BN, S)
{
    __shared__ float Et[64 * 65];
    __shared__ float Mred[4][64], Sred[4][64], Mfin[64], Rfin[64];

    const int t = threadIdx.x;
    const int bn0 = blockIdx.x * 64;
    const int lane = t & 63, w = t >> 6;

    // stage: Et[s][bn_loc], reads of e coalesced along bn
#pragma unroll
    for (int i = 0; i < 16; ++i) {
        int s = w * 16 + i;
        float v = (bn0 + lane < BN) ? e[s * BN + bn0 + lane] : 0.0f;
        Et[s * 65 + lane] = v;
    }
    __syncthreads();

    // per-bn max then sum(exp), 4 threads per bn
    {
        const int bn_loc = t & 63, sq = t >> 6;
        float m = -1e30f;
#pragma unroll
        for (int i = 0; i < 16; ++i)
            m = fmaxf(m, Et[(sq * 16 + i) * 65 + bn_loc]);
        Mred[sq][bn_loc] = m;
    }
    __syncthreads();
    {
        const int bn_loc = t & 63, sq = t >> 6;
        float m = fmaxf(fmaxf(Mred[0][bn_loc], Mred[1][bn_loc]),
                        fmaxf(Mred[2][bn_loc], Mred[3][bn_loc]));
        float sum = 0.0f;
#pragma unroll
        for (int i = 0; i < 16; ++i)
            sum += __expf(Et[(sq * 16 + i) * 65 + bn_loc] - m);
        Sred[sq][bn_loc] = sum;
        if (sq == 0) Mfin[bn_loc] = m;
    }
    __syncthreads();
    if ((t >> 6) == 0) {
        const int bn_loc = t & 63;
        float sum = Sred[0][bn_loc] + Sred[1][bn_loc] + Sred[2][bn_loc] + Sred[3][bn_loc];
        Rfin[bn_loc] = __builtin_amdgcn_rcpf(sum);
    }
    __syncthreads();

    // write out[bn][s], lanes -> s (coalesced)
    const int s_out = t & 63, bq = t >> 6;
#pragma unroll
    for (int j = 0; j < 16; ++j) {
        int bn_loc = bq * 16 + j;
        if (bn0 + bn_loc < BN) {
            float p = __expf(Et[s_out * 65 + bn_loc] - Mfin[bn_loc]) * Rfin[bn_loc];
            out[(bn0 + bn_loc) * S + s_out] = p;
        }
    }
}

extern "C" void kernel_launch(void* const* d_in, const int* in_sizes, int n_in,
                              void* d_out, int out_size, void* d_ws, size_t ws_size,
                              hipStream_t stream) {
    const float* enc  = (const float*)d_in[0];
    const float* dec  = (const float*)d_in[1];
    const float* W    = (const float*)d_in[2];
    const float* bias = (const float*)d_in[3];
    float* out        = (float*)d_out;

    uint4* wp = (uint4*)d_ws;                          // 16 KB
    float* e  = (float*)((char*)d_ws + 65536);         // 2.66 MB

    pack_w<<<2, 256, 0, stream>>>(W, wp);
    energy_k<<<NBLK, 256, 0, stream>>>(enc, dec, bias, wp, e);   // 10400 blocks
    softmax_k<<<(BN + 63) / 64, 256, 0, stream>>>(e, out);       // 163 blocks
}